// Round 13
// baseline (232.169 us; speedup 1.0000x reference)
//
#include <hip/hip_runtime.h>
#include <math.h>

// Problem constants
#define B_ 2
#define N_ 4096
#define C_ 256
#define H_ 4
#define DH_ 64
#define EPS_ 1e-6f
// 1/sqrt(DH) * log2(e), folded into Wq/bq so P = exp2(s) directly
#define SCALE_Q_ 0.18033688011112042f

typedef short bf16x8 __attribute__((ext_vector_type(8)));   // 8 bf16 in 4 VGPRs
typedef float f32x4 __attribute__((ext_vector_type(4)));
typedef int i32x4 __attribute__((ext_vector_type(4)));

// Only HW-verified gfx950 builtins, called directly — NO __has_builtin (host
// pass returns false for target builtins) and NO inline-asm trans ops (R6:
// asm v_exp_f32 defeats the trans-use hazard recognizer -> absmax 42.8).
// REGISTER RULE (R8, R11): at launch_bounds(512,4) the unified file splits
// 64 arch VGPR + 64 AGPR — only attnout's state fits. Anything bigger uses
// launch_bounds(256,2) or default.
#define MFMA32(a, b, c) __builtin_amdgcn_mfma_f32_16x16x32_bf16(a, b, c, 0, 0, 0)
#define FAST_EXP2(x) __builtin_amdgcn_exp2f(x)   // v_exp_f32, hazard-aware

__device__ __forceinline__ unsigned short f2bf(float x) {
  unsigned int u = __float_as_uint(x);
  return (unsigned short)((u + 0x7FFFu + ((u >> 16) & 1u)) >> 16);  // RNE
}
__device__ __forceinline__ float bf2f(unsigned short u) {
  return __uint_as_float(((unsigned int)u) << 16);
}
// Pack two floats to two bf16 (round-half-up) in one v_perm_b32.
__device__ __forceinline__ int pack2bf(float lo, float hi) {
  return (int)__builtin_amdgcn_perm(__float_as_uint(hi) + 0x8000u,
                                    __float_as_uint(lo) + 0x8000u, 0x07060302u);
}

// ---------------------------------------------------------------------------
// Kernel 1: weight transpose+cast to bf16 B-frag layout [n][k].
// ---------------------------------------------------------------------------
__global__ __launch_bounds__(256) void wconv_kernel(
    const float* __restrict__ Wq, const float* __restrict__ Wk,
    const float* __restrict__ Wv, const float* __restrict__ Wo,
    unsigned short* __restrict__ W3T, unsigned short* __restrict__ WoT) {
  const int base = blockIdx.x * 2048;
#pragma unroll
  for (int p = 0; p < 8; p++) {
    const int idx = base + p * 256 + threadIdx.x;
    if (idx < 196608) {
      const int m = idx >> 14;           // 0..11
      const int rem = idx & 16383;
      const int c = rem >> 6, d = rem & 63;
      const int h = m / 3, kind = m - h * 3;
      const float* W = kind == 0 ? Wq : kind == 1 ? Wk : Wv;
      float v = W[h * 16384 + rem];
      if (kind == 0) v *= SCALE_Q_;
      W3T[(h * 192 + kind * 64 + d) * 256 + c] = f2bf(v);
    } else {
      const int widx = idx - 196608;     // < 65536
      const int k = widx >> 8, n = widx & 255;
      WoT[n * 256 + k] = f2bf(Wo[widx]);
    }
  }
}

// ---------------------------------------------------------------------------
// Kernel 2 (MFMA, LN FUSED): h = LN(x+pos)*g+b computed in-block into a
// persistent 32KB LDS buffer (all four 64-k chunks), then q/k/v projections.
// Saves the ln launch + h16 global round-trip. LN: 4 lanes/row shuffle
// reduce; var = E[x^2]-mu^2 (fp32, cancellation negligible: E[x^2]~2,
// mu^2~0.01). x+pos re-read per head is L2-resident (16MB < 32MB L2).
// grid (128 rowtiles of 64, H) = 512 blocks (2/CU). Wave w owns 16 rows.
// ---------------------------------------------------------------------------
__global__ __launch_bounds__(256) void qkvln_kernel(
    const float* __restrict__ x, const float* __restrict__ pos,
    const float* __restrict__ g, const float* __restrict__ beta,
    const unsigned short* __restrict__ W3T,
    const float* __restrict__ bq, const float* __restrict__ bk,
    const float* __restrict__ bv,
    unsigned short* __restrict__ q16, unsigned short* __restrict__ k16,
    unsigned short* __restrict__ vT16) {
  const int rt = blockIdx.x;
  const int hh = blockIdx.y;
  const int t = threadIdx.x;
  const int w = t >> 6, lane = t & 63, c = lane & 15, quad = lane >> 4;
  __shared__ unsigned short Hs[4 * 64 * 64];   // 32 KB: [kt][row][64], swizzled
  __shared__ unsigned short Bs[192 * 64];      // 24 KB
  const int row0 = rt * 64;

  // --- LN prologue: thread (lrow, seg) covers cols [seg*64, seg*64+64) ---
  {
    const int lrow = t >> 2, seg = t & 3;
    const size_t base = (size_t)(row0 + lrow) * C_ + seg * 64;
    float sum = 0.f, ssq = 0.f;
#pragma unroll
    for (int k4 = 0; k4 < 16; k4++) {
      const float4 xv = *(const float4*)&x[base + k4 * 4];
      const float4 pv = *(const float4*)&pos[base + k4 * 4];
      const float v0 = xv.x + pv.x, v1 = xv.y + pv.y;
      const float v2 = xv.z + pv.z, v3 = xv.w + pv.w;
      sum += v0 + v1 + v2 + v3;
      ssq += v0 * v0 + v1 * v1 + v2 * v2 + v3 * v3;
    }
    // combine the 4 lanes of this row (lanes differ in bits 0-1)
    sum += __shfl_xor(sum, 1); sum += __shfl_xor(sum, 2);
    ssq += __shfl_xor(ssq, 1); ssq += __shfl_xor(ssq, 2);
    const float mu = sum * (1.0f / C_);
    const float var = fmaxf(ssq * (1.0f / C_) - mu * mu, 0.0f);
    const float rs = rsqrtf(var + EPS_);
#pragma unroll
    for (int k8 = 0; k8 < 8; k8++) {
      const float4 xa = *(const float4*)&x[base + k8 * 8];
      const float4 pa = *(const float4*)&pos[base + k8 * 8];
      const float4 xb = *(const float4*)&x[base + k8 * 8 + 4];
      const float4 pb = *(const float4*)&pos[base + k8 * 8 + 4];
      const float4 ga = *(const float4*)&g[seg * 64 + k8 * 8];
      const float4 gb = *(const float4*)&g[seg * 64 + k8 * 8 + 4];
      const float4 ba = *(const float4*)&beta[seg * 64 + k8 * 8];
      const float4 bb = *(const float4*)&beta[seg * 64 + k8 * 8 + 4];
      bf16x8 o;
      o[0] = (short)f2bf((xa.x + pa.x - mu) * rs * ga.x + ba.x);
      o[1] = (short)f2bf((xa.y + pa.y - mu) * rs * ga.y + ba.y);
      o[2] = (short)f2bf((xa.z + pa.z - mu) * rs * ga.z + ba.z);
      o[3] = (short)f2bf((xa.w + pa.w - mu) * rs * ga.w + ba.w);
      o[4] = (short)f2bf((xb.x + pb.x - mu) * rs * gb.x + bb.x);
      o[5] = (short)f2bf((xb.y + pb.y - mu) * rs * gb.y + bb.y);
      o[6] = (short)f2bf((xb.z + pb.z - mu) * rs * gb.z + bb.z);
      o[7] = (short)f2bf((xb.w + pb.w - mu) * rs * gb.w + bb.w);
      *(bf16x8*)&Hs[seg * 4096 + lrow * 64 + ((k8 ^ (lrow & 7)) * 8)] = o;
    }
  }
  __syncthreads();

  f32x4 acc[12];
#pragma unroll
  for (int nt = 0; nt < 12; nt++) acc[nt] = (f32x4){0.f, 0.f, 0.f, 0.f};

  for (int kt4 = 0; kt4 < 4; kt4++) {
    __syncthreads();
#pragma unroll
    for (int p = 0; p < 6; p++) {
      const int e = t + p * 256;
      const int row = e >> 3, ch = e & 7;
      *(bf16x8*)&Bs[row * 64 + ((ch ^ (row & 7)) * 8)] =
          *(const bf16x8*)&W3T[(size_t)(hh * 192 + row) * C_ + kt4 * 64 + ch * 8];
    }
    __syncthreads();
#pragma unroll
    for (int kh = 0; kh < 2; kh++) {
      const int i = w * 16 + c;
      bf16x8 a = *(const bf16x8*)&Hs[kt4 * 4096 + i * 64 + (((kh * 4 + quad) ^ (i & 7)) * 8)];
#pragma unroll
      for (int nt = 0; nt < 12; nt++) {
        const int n = nt * 16 + c;
        bf16x8 b = *(const bf16x8*)&Bs[n * 64 + (((kh * 4 + quad) ^ (n & 7)) * 8)];
        acc[nt] = MFMA32(a, b, acc[nt]);
      }
    }
  }
#pragma unroll
  for (int nt = 0; nt < 12; nt++) {
    const int kind = nt >> 2;
    const int col = (nt & 3) * 16 + c;
    const float bias = kind == 0 ? bq[hh * 64 + col] * SCALE_Q_
                     : kind == 1 ? bk[hh * 64 + col] : bv[hh * 64 + col];
#pragma unroll
    for (int r = 0; r < 4; r++) {
      const int gr = row0 + w * 16 + quad * 4 + r;
      const int b = gr >> 12, n = gr & (N_ - 1);
      const size_t bh = (size_t)(b * H_ + hh);
      const unsigned short val = f2bf(acc[nt][r] + bias);
      if (kind == 0)      q16[(bh * N_ + n) * DH_ + col] = val;
      else if (kind == 1) k16[(bh * N_ + n) * DH_ + col] = val;
      else                vT16[(bh * DH_ + col) * N_ + n] = val;
    }
  }
}

// ---------------------------------------------------------------------------
// Kernel 3 (MFMA): l_j = sum_i exp2(s~_ij); vT16 *= 1/l in place.
// R7-PROVEN version [R12, unchanged]: grid 512 x 256 thr, launch_bounds(256,2).
// ---------------------------------------------------------------------------
__global__ __launch_bounds__(256, 2) void colstats_kernel(
    const unsigned short* __restrict__ q16, const unsigned short* __restrict__ k16,
    unsigned short* __restrict__ vT16) {
  const int blk = blockIdx.x;
  const int bh = blk & 7;
  const int j0 = (blk >> 3) * 64;
  const int t = threadIdx.x;
  const int w = t >> 6, lane = t & 63, c = lane & 15, quad = lane >> 4;
  __shared__ unsigned short Qs[64 * 64];
  __shared__ float Lp[4][64];
  __shared__ float ilv[64];

  bf16x8 ka[4][2];
#pragma unroll
  for (int jb = 0; jb < 4; jb++) {
    const size_t kb = ((size_t)bh * N_ + j0 + jb * 16 + c) * DH_;
    ka[jb][0] = *(const bf16x8*)&k16[kb + quad * 8];
    ka[jb][1] = *(const bf16x8*)&k16[kb + 32 + quad * 8];
  }

  bf16x8 pre[2];
  auto loadQ = [&](int i0) {
#pragma unroll
    for (int p = 0; p < 2; p++) {
      const int e = t + p * 256;
      const int row = e >> 3, ch = e & 7;
      pre[p] = *(const bf16x8*)&q16[((size_t)bh * N_ + i0 + row) * DH_ + ch * 8];
    }
  };
  loadQ(0);

  f32x4 lsum[4];
#pragma unroll
  for (int jb = 0; jb < 4; jb++) lsum[jb] = (f32x4){0.f, 0.f, 0.f, 0.f};

  for (int i0 = 0; i0 < N_; i0 += 64) {
    __syncthreads();
#pragma unroll
    for (int p = 0; p < 2; p++) {
      const int e = t + p * 256;
      const int row = e >> 3, ch = e & 7;
      *(bf16x8*)&Qs[row * 64 + ((ch ^ (row & 7)) * 8)] = pre[p];
    }
    __syncthreads();
    if (i0 + 64 < N_) loadQ(i0 + 64);
    const int ir = w * 16 + c;
    bf16x8 qf0 = *(const bf16x8*)&Qs[ir * 64 + ((quad ^ (c & 7)) * 8)];
    bf16x8 qf1 = *(const bf16x8*)&Qs[ir * 64 + (((4 + quad) ^ (c & 7)) * 8)];
#pragma unroll
    for (int jb = 0; jb < 4; jb++) {
      f32x4 s = {0.f, 0.f, 0.f, 0.f};
      s = MFMA32(ka[jb][0], qf0, s);
      s = MFMA32(ka[jb][1], qf1, s);
#pragma unroll
      for (int r = 0; r < 4; r++) lsum[jb][r] += FAST_EXP2(s[r]);
    }
  }
#pragma unroll
  for (int jb = 0; jb < 4; jb++) {
#pragma unroll
    for (int r = 0; r < 4; r++) {
      float s = lsum[jb][r];
      s += __shfl_xor(s, 1); s += __shfl_xor(s, 2);
      s += __shfl_xor(s, 4); s += __shfl_xor(s, 8);
      if (c == 0) Lp[w][jb * 16 + quad * 4 + r] = s;
    }
  }
  __syncthreads();
  if (t < 64) ilv[t] = 1.0f / (Lp[0][t] + Lp[1][t] + Lp[2][t] + Lp[3][t]);
  __syncthreads();
#pragma unroll
  for (int p = 0; p < 2; p++) {
    const int e = t + p * 256;
    const int d = e >> 3, ch = e & 7;
    const size_t addr = ((size_t)bh * DH_ + d) * N_ + j0 + ch * 8;
    bf16x8 v = *(const bf16x8*)&vT16[addr];
#pragma unroll
    for (int jj = 0; jj < 8; jj++)
      v[jj] = (short)f2bf(bf2f((unsigned short)v[jj]) * ilv[ch * 8 + jj]);
    *(bf16x8*)&vT16[addr] = v;
  }
}

// ---------------------------------------------------------------------------
// Kernel 4 (MFMA): O[i,d] = sum_j exp2(s~_ij) * V~[j,d]     [R9/R12, unchanged]
// grid 512 x 512 thr (8 waves), launch_bounds(512,4) -> 16 waves/CU.
// 2-D wave split keeps regs <=64+64: iw owns 32 i, jw owns a 32-j window.
// ---------------------------------------------------------------------------
__global__ __launch_bounds__(512, 4) void attnout_kernel(
    const unsigned short* __restrict__ q16, const unsigned short* __restrict__ k16,
    const unsigned short* __restrict__ vT16, unsigned short* __restrict__ ob16) {
  const int blk = blockIdx.x;
  const int bh = blk & 7;
  const int bb = bh >> 2, hh = bh & 3;
  const int i0 = (blk >> 3) * 64;
  const int t = threadIdx.x;
  const int w = t >> 6, lane = t & 63, c = lane & 15, quad = lane >> 4;
  const int iw = w >> 2;           // 0..1: 32-i half
  const int jw = w & 3;            // 0..3: 32-j window of the 128-j stage

  __shared__ __align__(16) char smem[32768];              // Ks 16K | Vs 16K
  unsigned short* Ks = (unsigned short*)smem;             // [128 j][64 d], swz ch^((j>>2)&7)
  unsigned short* Vs = (unsigned short*)smem + 128 * 64;  // [64 d][128 j], swz ch^(d&15)
  float* Rf = (float*)smem;                               // reduce: 4 x 8KB regions

  // Q B-frags: rows i = i0 + iw*32 + ib*16 + c
  bf16x8 qa[2][2];
#pragma unroll
  for (int ib = 0; ib < 2; ib++) {
    const size_t qb = ((size_t)bh * N_ + i0 + iw * 32 + ib * 16 + c) * DH_;
    qa[ib][0] = *(const bf16x8*)&q16[qb + quad * 8];
    qa[ib][1] = *(const bf16x8*)&q16[qb + 32 + quad * 8];
  }

  bf16x8 kpre[2], vpre[2];
  auto loadKV = [&](int jt) {
#pragma unroll
    for (int p = 0; p < 2; p++) {
      const int e = t + p * 512;
      kpre[p] = *(const bf16x8*)&k16[((size_t)bh * N_ + jt + (e >> 3)) * DH_ + (e & 7) * 8];
      vpre[p] = *(const bf16x8*)&vT16[((size_t)bh * DH_ + (e >> 4)) * N_ + jt + (e & 15) * 8];
    }
  };
  loadKV(0);

  f32x4 of[2][4];
#pragma unroll
  for (int ib = 0; ib < 2; ib++)
#pragma unroll
    for (int dt = 0; dt < 4; dt++) of[ib][dt] = (f32x4){0.f, 0.f, 0.f, 0.f};

  for (int jt = 0; jt < N_; jt += 128) {
    __syncthreads();
#pragma unroll
    for (int p = 0; p < 2; p++) {
      const int e = t + p * 512;
      { const int row = e >> 3, ch = e & 7;      // K: 128 rows x 8 chunks
        *(bf16x8*)&Ks[row * 64 + ((ch ^ ((row >> 2) & 7)) * 8)] = kpre[p]; }
      { const int d = e >> 4, ch = e & 15;       // V: 64 d-rows x 16 chunks
        *(bf16x8*)&Vs[d * 128 + ((ch ^ (d & 15)) * 8)] = vpre[p]; }
    }
    __syncthreads();
    if (jt + 128 < N_) loadKV(jt + 128);   // in flight during compute

    // Permuted K A-frags for window jw: m=c -> j-local jw*32 + 8*(c>>2)+s*4+(c&3)
    bf16x8 kf[2][2];
#pragma unroll
    for (int s = 0; s < 2; s++) {
      const int jr = jw * 32 + ((c >> 2) * 8) + s * 4 + (c & 3);
      const int swz = (jr >> 2) & 7;
      kf[s][0] = *(const bf16x8*)&Ks[jr * 64 + ((quad ^ swz) * 8)];
      kf[s][1] = *(const bf16x8*)&Ks[jr * 64 + (((4 + quad) ^ swz) * 8)];
    }
    // V B-frags: B[n=d][k=jj] = V~T[d][jw*32 + quad*8 + jj]
    bf16x8 vf[4];
#pragma unroll
    for (int dt = 0; dt < 4; dt++) {
      const int d = dt * 16 + c;
      vf[dt] = *(const bf16x8*)&Vs[d * 128 + (((jw * 4 + quad) ^ (d & 15)) * 8)];
    }

#pragma unroll
    for (int ib = 0; ib < 2; ib++) {
      // S^T halves: D[m][n=i=c]; set s covers j-local jw*32 + 8*quad + s*4 + r
      f32x4 s0 = {0.f, 0.f, 0.f, 0.f}, s1 = {0.f, 0.f, 0.f, 0.f};
      s0 = MFMA32(kf[0][0], qa[ib][0], s0);
      s0 = MFMA32(kf[0][1], qa[ib][1], s0);
      s1 = MFMA32(kf[1][0], qa[ib][0], s1);
      s1 = MFMA32(kf[1][1], qa[ib][1], s1);
      // P A-frag via v_exp + v_perm pair-pack: pf[jj] = P[i=c][jw*32+quad*8+jj]
      i32x4 pi;
      pi[0] = pack2bf(FAST_EXP2(s0[0]), FAST_EXP2(s0[1]));
      pi[1] = pack2bf(FAST_EXP2(s0[2]), FAST_EXP2(s0[3]));
      pi[2] = pack2bf(FAST_EXP2(s1[0]), FAST_EXP2(s1[1]));
      pi[3] = pack2bf(FAST_EXP2(s1[2]), FAST_EXP2(s1[3]));
      bf16x8 pf = *(bf16x8*)&pi;
#pragma unroll
      for (int dt = 0; dt < 4; dt++)
        of[ib][dt] = MFMA32(pf, vf[dt], of[ib][dt]);
    }
  }

  // Tree reduce over the 4 jw-waves per i-half (disjoint j). Ks/Vs dead.
  __syncthreads();
  if (jw >= 2) {
    float* dst = Rf + (iw * 2 + (jw - 2)) * 2048;
#pragma unroll
    for (int ib = 0; ib < 2; ib++)
#pragma unroll
      for (int dt = 0; dt < 4; dt++)
        *(f32x4*)&dst[lane * 32 + (((ib * 4 + dt) ^ (lane & 7)) * 4)] = of[ib][dt];
  }
  __syncthreads();
  if (jw < 2) {
    const float* src = Rf + (iw * 2 + jw) * 2048;
#pragma unroll
    for (int ib = 0; ib < 2; ib++)
#pragma unroll
      for (int dt = 0; dt < 4; dt++)
        of[ib][dt] += *(const f32x4*)&src[lane * 32 + (((ib * 4 + dt) ^ (lane & 7)) * 4)];
  }
  __syncthreads();
  if (jw == 1) {
    float* dst = Rf + iw * 2048;
#pragma unroll
    for (int ib = 0; ib < 2; ib++)
#pragma unroll
      for (int dt = 0; dt < 4; dt++)
        *(f32x4*)&dst[lane * 32 + (((ib * 4 + dt) ^ (lane & 7)) * 4)] = of[ib][dt];
  }
  __syncthreads();
  if (jw == 0) {
    const float* src = Rf + iw * 2048;
#pragma unroll
    for (int ib = 0; ib < 2; ib++)
#pragma unroll
      for (int dt = 0; dt < 4; dt++) {
        of[ib][dt] += *(const f32x4*)&src[lane * 32 + (((ib * 4 + dt) ^ (lane & 7)) * 4)];
#pragma unroll
        for (int r = 0; r < 4; r++)
          ob16[((size_t)bb * N_ + i0 + iw * 32 + ib * 16 + quad * 4 + r) * C_ +
               hh * DH_ + dt * 16 + c] = f2bf(of[ib][dt][r]);
      }
  }
}

// ---------------------------------------------------------------------------
// Kernel 5 (MFMA): out = o @ Wo + bo  (fp32 out).
// grid (256 rowtiles of 32, 2 col-halves of 128) = 512 blocks -> 2 blocks/CU
// (was 256 = 1/CU). Wave w owns 32 cols of the staged 128. LDS 20 KB.
// ---------------------------------------------------------------------------
__global__ __launch_bounds__(256) void outproj_kernel(
    const unsigned short* __restrict__ ob16, const unsigned short* __restrict__ WoT,
    const float* __restrict__ bo, float* __restrict__ out) {
  const int rt = blockIdx.x;
  const int ch2 = blockIdx.y;
  const int t = threadIdx.x;
  const int w = t >> 6, lane = t & 63, c = lane & 15, quad = lane >> 4;
  __shared__ unsigned short As[32 * 64];    // 4 KB
  __shared__ unsigned short Bs[128 * 64];   // 16 KB

  f32x4 acc[2][2];
#pragma unroll
  for (int mt = 0; mt < 2; mt++)
#pragma unroll
    for (int nt = 0; nt < 2; nt++) acc[mt][nt] = (f32x4){0.f, 0.f, 0.f, 0.f};

  for (int kt = 0; kt < C_; kt += 64) {
    __syncthreads();
    {
      const int row = t >> 3, ch = t & 7;
      *(bf16x8*)&As[row * 64 + ((ch ^ (row & 7)) * 8)] =
          *(const bf16x8*)&ob16[((size_t)rt * 32 + row) * C_ + kt + ch * 8];
    }
#pragma unroll
    for (int p = 0; p < 4; p++) {
      const int e = t + p * 256;
      const int row = e >> 3, ch = e & 7;
      *(bf16x8*)&Bs[row * 64 + ((ch ^ (row & 7)) * 8)] =
          *(const bf16x8*)&WoT[(size_t)(ch2 * 128 + row) * C_ + kt + ch * 8];
    }
    __syncthreads();
#pragma unroll
    for (int kh = 0; kh < 2; kh++) {
      bf16x8 a[2];
#pragma unroll
      for (int mt = 0; mt < 2; mt++) {
        const int i = mt * 16 + c;
        a[mt] = *(const bf16x8*)&As[i * 64 + (((kh * 4 + quad) ^ (i & 7)) * 8)];
      }
#pragma unroll
      for (int nt = 0; nt < 2; nt++) {
        const int n = w * 32 + nt * 16 + c;
        bf16x8 b = *(const bf16x8*)&Bs[n * 64 + (((kh * 4 + quad) ^ (n & 7)) * 8)];
        acc[0][nt] = MFMA32(a[0], b, acc[0][nt]);
        acc[1][nt] = MFMA32(a[1], b, acc[1][nt]);
      }
    }
  }
#pragma unroll
  for (int mt = 0; mt < 2; mt++)
#pragma unroll
    for (int nt = 0; nt < 2; nt++) {
      const int col = ch2 * 128 + w * 32 + nt * 16 + c;
      const float bias = bo[col];
#pragma unroll
      for (int r = 0; r < 4; r++)
        out[((size_t)rt * 32 + mt * 16 + quad * 4 + r) * C_ + col] = acc[mt][nt][r] + bias;
    }
}

// ---------------------------------------------------------------------------
extern "C" void kernel_launch(void* const* d_in, const int* in_sizes, int n_in,
                              void* d_out, int out_size, void* d_ws, size_t ws_size,
                              hipStream_t stream) {
  const float* x    = (const float*)d_in[0];
  const float* pos  = (const float*)d_in[1];
  const float* Wq   = (const float*)d_in[2];
  const float* bq   = (const float*)d_in[3];
  const float* Wk   = (const float*)d_in[4];
  const float* bk   = (const float*)d_in[5];
  const float* Wv   = (const float*)d_in[6];
  const float* bv   = (const float*)d_in[7];
  const float* Wo   = (const float*)d_in[8];
  const float* bo   = (const float*)d_in[9];
  const float* ln_g = (const float*)d_in[10];
  const float* ln_b = (const float*)d_in[11];
  float* out = (float*)d_out;

  // Workspace (u16): q16|k16|vT16|ob16 (2M each) | W3T 196608 | WoT 65536
  const size_t SZ = (size_t)B_ * N_ * C_;   // 2097152
  unsigned short* q16  = (unsigned short*)d_ws;
  unsigned short* k16  = q16 + SZ;
  unsigned short* vT16 = k16 + SZ;
  unsigned short* ob16 = vT16 + SZ;
  unsigned short* W3T  = ob16 + SZ;
  unsigned short* WoT  = W3T + (size_t)H_ * 192 * 256;

  wconv_kernel<<<128, 256, 0, stream>>>(Wq, Wk, Wv, Wo, W3T, WoT);
  qkvln_kernel<<<dim3(128, H_), 256, 0, stream>>>(
      x, pos, ln_g, ln_b, W3T, bq, bk, bv, q16, k16, vT16);
  colstats_kernel<<<512, 256, 0, stream>>>(q16, k16, vT16);
  attnout_kernel<<<512, 512, 0, stream>>>(q16, k16, vT16, ob16);
  outproj_kernel<<<dim3(256, 2), 256, 0, stream>>>(ob16, WoT, bo, out);
}

// Round 14
// 184.540 us; speedup vs baseline: 1.2581x; 1.2581x over previous
//
#include <hip/hip_runtime.h>
#include <math.h>

// Problem constants
#define B_ 2
#define N_ 4096
#define C_ 256
#define H_ 4
#define DH_ 64
#define EPS_ 1e-6f
// 1/sqrt(DH) * log2(e), folded into Wq/bq so P = exp2(s) directly
#define SCALE_Q_ 0.18033688011112042f

typedef short bf16x8 __attribute__((ext_vector_type(8)));   // 8 bf16 in 4 VGPRs
typedef short bf16x4v __attribute__((ext_vector_type(4)));  // 4 bf16 in 2 VGPRs
typedef float f32x4 __attribute__((ext_vector_type(4)));
typedef int i32x4 __attribute__((ext_vector_type(4)));

// Only HW-verified gfx950 builtins, called directly — NO __has_builtin (host
// pass returns false for target builtins) and NO inline-asm trans ops (R6).
// REGISTER RULE (R8, R11): at launch_bounds(512,4) the unified file splits
// 64 arch VGPR + 64 AGPR — only attnout's state fits. Anything bigger uses
// launch_bounds(256,2) or default.
// FUSION RULE (R13): don't serialize a latency-bound prologue in front of
// MFMA work inside one block — separate kernels hide it across blocks.
#define MFMA32(a, b, c) __builtin_amdgcn_mfma_f32_16x16x32_bf16(a, b, c, 0, 0, 0)
#define FAST_EXP2(x) __builtin_amdgcn_exp2f(x)   // v_exp_f32, hazard-aware

__device__ __forceinline__ unsigned short f2bf(float x) {
  unsigned int u = __float_as_uint(x);
  return (unsigned short)((u + 0x7FFFu + ((u >> 16) & 1u)) >> 16);  // RNE
}
__device__ __forceinline__ float bf2f(unsigned short u) {
  return __uint_as_float(((unsigned int)u) << 16);
}
// Pack two floats to two bf16 (round-half-up) in one v_perm_b32.
__device__ __forceinline__ int pack2bf(float lo, float hi) {
  return (int)__builtin_amdgcn_perm(__float_as_uint(hi) + 0x8000u,
                                    __float_as_uint(lo) + 0x8000u, 0x07060302u);
}

// ---------------------------------------------------------------------------
// Kernel 1: h16 = bf16(LayerNorm(x + pos) * g + b)
// Wave-per-row: float4 loads, pure shuffle reduce, no LDS/barriers. grid 2048.
// ---------------------------------------------------------------------------
__global__ __launch_bounds__(256) void ln_kernel(
    const float* __restrict__ x, const float* __restrict__ pos,
    const float* __restrict__ g, const float* __restrict__ beta,
    unsigned short* __restrict__ h16) {
  const int w = threadIdx.x >> 6, lane = threadIdx.x & 63;
  const int row = blockIdx.x * 4 + w;
  const float4 xv = *(const float4*)&x[row * C_ + lane * 4];
  const float4 pv = *(const float4*)&pos[row * C_ + lane * 4];
  float4 v = {xv.x + pv.x, xv.y + pv.y, xv.z + pv.z, xv.w + pv.w};
  float s = v.x + v.y + v.z + v.w;
  s += __shfl_xor(s, 1);  s += __shfl_xor(s, 2);  s += __shfl_xor(s, 4);
  s += __shfl_xor(s, 8);  s += __shfl_xor(s, 16); s += __shfl_xor(s, 32);
  const float mu = s * (1.0f / C_);
  float4 d = {v.x - mu, v.y - mu, v.z - mu, v.w - mu};
  float q = d.x * d.x + d.y * d.y + d.z * d.z + d.w * d.w;
  q += __shfl_xor(q, 1);  q += __shfl_xor(q, 2);  q += __shfl_xor(q, 4);
  q += __shfl_xor(q, 8);  q += __shfl_xor(q, 16); q += __shfl_xor(q, 32);
  const float rs = rsqrtf(q * (1.0f / C_) + EPS_);
  const float4 g4 = *(const float4*)&g[lane * 4];
  const float4 b4 = *(const float4*)&beta[lane * 4];
  bf16x4v o;
  o[0] = (short)f2bf(d.x * rs * g4.x + b4.x);
  o[1] = (short)f2bf(d.y * rs * g4.y + b4.y);
  o[2] = (short)f2bf(d.z * rs * g4.z + b4.z);
  o[3] = (short)f2bf(d.w * rs * g4.w + b4.w);
  *(bf16x4v*)&h16[row * C_ + lane * 4] = o;
}

// ---------------------------------------------------------------------------
// Kernel 2: weight transpose+cast to bf16 B-frag layout [n][k].
// ---------------------------------------------------------------------------
__global__ __launch_bounds__(256) void wconv_kernel(
    const float* __restrict__ Wq, const float* __restrict__ Wk,
    const float* __restrict__ Wv, const float* __restrict__ Wo,
    unsigned short* __restrict__ W3T, unsigned short* __restrict__ WoT) {
  const int base = blockIdx.x * 2048;
#pragma unroll
  for (int p = 0; p < 8; p++) {
    const int idx = base + p * 256 + threadIdx.x;
    if (idx < 196608) {
      const int m = idx >> 14;           // 0..11
      const int rem = idx & 16383;
      const int c = rem >> 6, d = rem & 63;
      const int h = m / 3, kind = m - h * 3;
      const float* W = kind == 0 ? Wq : kind == 1 ? Wk : Wv;
      float v = W[h * 16384 + rem];
      if (kind == 0) v *= SCALE_Q_;
      W3T[(h * 192 + kind * 64 + d) * 256 + c] = f2bf(v);
    } else {
      const int widx = idx - 196608;     // < 65536
      const int k = widx >> 8, n = widx & 255;
      WoT[n * 256 + k] = f2bf(Wo[widx]);
    }
  }
}

// ---------------------------------------------------------------------------
// Kernel 3 (MFMA): q/k/v projections.  q16,k16: [bh][n][64]; vT16: [bh][64][N]
// 64-row tiles, grid (128, H) = 512 blocks (2/CU). Wave w owns 16 rows.
// ---------------------------------------------------------------------------
__global__ __launch_bounds__(256) void qkv_kernel(
    const unsigned short* __restrict__ h16, const unsigned short* __restrict__ W3T,
    const float* __restrict__ bq, const float* __restrict__ bk,
    const float* __restrict__ bv,
    unsigned short* __restrict__ q16, unsigned short* __restrict__ k16,
    unsigned short* __restrict__ vT16) {
  const int rt = blockIdx.x;
  const int hh = blockIdx.y;
  const int t = threadIdx.x;
  const int w = t >> 6, lane = t & 63, c = lane & 15, quad = lane >> 4;
  __shared__ unsigned short Hs[64 * 64];    // 8 KB
  __shared__ unsigned short Bs[192 * 64];   // 24 KB
  const int row0 = rt * 64;

  f32x4 acc[12];
#pragma unroll
  for (int nt = 0; nt < 12; nt++) acc[nt] = (f32x4){0.f, 0.f, 0.f, 0.f};

  for (int kt = 0; kt < C_; kt += 64) {
    __syncthreads();
#pragma unroll
    for (int p = 0; p < 2; p++) {
      const int e = t + p * 256;
      const int row = e >> 3, ch = e & 7;
      *(bf16x8*)&Hs[row * 64 + ((ch ^ (row & 7)) * 8)] =
          *(const bf16x8*)&h16[(size_t)(row0 + row) * C_ + kt + ch * 8];
    }
#pragma unroll
    for (int p = 0; p < 6; p++) {
      const int e = t + p * 256;
      const int row = e >> 3, ch = e & 7;
      *(bf16x8*)&Bs[row * 64 + ((ch ^ (row & 7)) * 8)] =
          *(const bf16x8*)&W3T[(size_t)(hh * 192 + row) * C_ + kt + ch * 8];
    }
    __syncthreads();
#pragma unroll
    for (int kh = 0; kh < 2; kh++) {
      const int i = w * 16 + c;
      bf16x8 a = *(const bf16x8*)&Hs[i * 64 + (((kh * 4 + quad) ^ (i & 7)) * 8)];
#pragma unroll
      for (int nt = 0; nt < 12; nt++) {
        const int n = nt * 16 + c;
        bf16x8 b = *(const bf16x8*)&Bs[n * 64 + (((kh * 4 + quad) ^ (n & 7)) * 8)];
        acc[nt] = MFMA32(a, b, acc[nt]);
      }
    }
  }
#pragma unroll
  for (int nt = 0; nt < 12; nt++) {
    const int kind = nt >> 2;
    const int col = (nt & 3) * 16 + c;
    const float bias = kind == 0 ? bq[hh * 64 + col] * SCALE_Q_
                     : kind == 1 ? bk[hh * 64 + col] : bv[hh * 64 + col];
#pragma unroll
    for (int r = 0; r < 4; r++) {
      const int gr = row0 + w * 16 + quad * 4 + r;
      const int b = gr >> 12, n = gr & (N_ - 1);
      const size_t bh = (size_t)(b * H_ + hh);
      const unsigned short val = f2bf(acc[nt][r] + bias);
      if (kind == 0)      q16[(bh * N_ + n) * DH_ + col] = val;
      else if (kind == 1) k16[(bh * N_ + n) * DH_ + col] = val;
      else                vT16[(bh * DH_ + col) * N_ + n] = val;
    }
  }
}

// ---------------------------------------------------------------------------
// Kernel 4 (MFMA): l_j = sum_i exp2(s~_ij); vT16 *= 1/l in place.
// R7 machinery, 32-j blocks: grid 1024 (bh = blk&7, 32 cols) x 256 thr,
// launch_bounds(256,2) — R12's grid of 512 capped occupancy at 2 blocks/CU
// BY GRID SIZE; 1024 blocks -> 4 blocks/CU, 16 waves/CU, VGPR shrinks
// (ka[2][2]=16). Inner stage structure identical to the proven R7 version.
// ---------------------------------------------------------------------------
__global__ __launch_bounds__(256, 2) void colstats_kernel(
    const unsigned short* __restrict__ q16, const unsigned short* __restrict__ k16,
    unsigned short* __restrict__ vT16) {
  const int blk = blockIdx.x;
  const int bh = blk & 7;
  const int j0 = (blk >> 3) * 32;
  const int t = threadIdx.x;
  const int w = t >> 6, lane = t & 63, c = lane & 15, quad = lane >> 4;
  __shared__ unsigned short Qs[64 * 64];
  __shared__ float Lp[4][32];
  __shared__ float ilv[32];

  bf16x8 ka[2][2];
#pragma unroll
  for (int jb = 0; jb < 2; jb++) {
    const size_t kb = ((size_t)bh * N_ + j0 + jb * 16 + c) * DH_;
    ka[jb][0] = *(const bf16x8*)&k16[kb + quad * 8];
    ka[jb][1] = *(const bf16x8*)&k16[kb + 32 + quad * 8];
  }

  bf16x8 pre[2];
  auto loadQ = [&](int i0) {
#pragma unroll
    for (int p = 0; p < 2; p++) {
      const int e = t + p * 256;
      const int row = e >> 3, ch = e & 7;
      pre[p] = *(const bf16x8*)&q16[((size_t)bh * N_ + i0 + row) * DH_ + ch * 8];
    }
  };
  loadQ(0);

  f32x4 lsum[2];
#pragma unroll
  for (int jb = 0; jb < 2; jb++) lsum[jb] = (f32x4){0.f, 0.f, 0.f, 0.f};

  for (int i0 = 0; i0 < N_; i0 += 64) {
    __syncthreads();
#pragma unroll
    for (int p = 0; p < 2; p++) {
      const int e = t + p * 256;
      const int row = e >> 3, ch = e & 7;
      *(bf16x8*)&Qs[row * 64 + ((ch ^ (row & 7)) * 8)] = pre[p];
    }
    __syncthreads();
    if (i0 + 64 < N_) loadQ(i0 + 64);
    const int ir = w * 16 + c;
    bf16x8 qf0 = *(const bf16x8*)&Qs[ir * 64 + ((quad ^ (c & 7)) * 8)];
    bf16x8 qf1 = *(const bf16x8*)&Qs[ir * 64 + (((4 + quad) ^ (c & 7)) * 8)];
#pragma unroll
    for (int jb = 0; jb < 2; jb++) {
      f32x4 s = {0.f, 0.f, 0.f, 0.f};
      s = MFMA32(ka[jb][0], qf0, s);
      s = MFMA32(ka[jb][1], qf1, s);
#pragma unroll
      for (int r = 0; r < 4; r++) lsum[jb][r] += FAST_EXP2(s[r]);
    }
  }
#pragma unroll
  for (int jb = 0; jb < 2; jb++) {
#pragma unroll
    for (int r = 0; r < 4; r++) {
      float s = lsum[jb][r];
      s += __shfl_xor(s, 1); s += __shfl_xor(s, 2);
      s += __shfl_xor(s, 4); s += __shfl_xor(s, 8);
      if (c == 0) Lp[w][jb * 16 + quad * 4 + r] = s;
    }
  }
  __syncthreads();
  if (t < 32) ilv[t] = 1.0f / (Lp[0][t] + Lp[1][t] + Lp[2][t] + Lp[3][t]);
  __syncthreads();
  // Scale this block's private 32-col vT16 slice in place: V~ = invl_j * V
  {
    const int d = t >> 2, ch = t & 3;
    const size_t addr = ((size_t)bh * DH_ + d) * N_ + j0 + ch * 8;
    bf16x8 v = *(const bf16x8*)&vT16[addr];
#pragma unroll
    for (int jj = 0; jj < 8; jj++)
      v[jj] = (short)f2bf(bf2f((unsigned short)v[jj]) * ilv[ch * 8 + jj]);
    *(bf16x8*)&vT16[addr] = v;
  }
}

// ---------------------------------------------------------------------------
// Kernel 5 (MFMA): O[i,d] = sum_j exp2(s~_ij) * V~[j,d]     [R9/R12, unchanged]
// grid 512 x 512 thr (8 waves), launch_bounds(512,4) -> 16 waves/CU.
// 2-D wave split keeps regs <=64+64: iw owns 32 i, jw owns a 32-j window.
// ---------------------------------------------------------------------------
__global__ __launch_bounds__(512, 4) void attnout_kernel(
    const unsigned short* __restrict__ q16, const unsigned short* __restrict__ k16,
    const unsigned short* __restrict__ vT16, unsigned short* __restrict__ ob16) {
  const int blk = blockIdx.x;
  const int bh = blk & 7;
  const int bb = bh >> 2, hh = bh & 3;
  const int i0 = (blk >> 3) * 64;
  const int t = threadIdx.x;
  const int w = t >> 6, lane = t & 63, c = lane & 15, quad = lane >> 4;
  const int iw = w >> 2;           // 0..1: 32-i half
  const int jw = w & 3;            // 0..3: 32-j window of the 128-j stage

  __shared__ __align__(16) char smem[32768];              // Ks 16K | Vs 16K
  unsigned short* Ks = (unsigned short*)smem;             // [128 j][64 d], swz ch^((j>>2)&7)
  unsigned short* Vs = (unsigned short*)smem + 128 * 64;  // [64 d][128 j], swz ch^(d&15)
  float* Rf = (float*)smem;                               // reduce: 4 x 8KB regions

  // Q B-frags: rows i = i0 + iw*32 + ib*16 + c
  bf16x8 qa[2][2];
#pragma unroll
  for (int ib = 0; ib < 2; ib++) {
    const size_t qb = ((size_t)bh * N_ + i0 + iw * 32 + ib * 16 + c) * DH_;
    qa[ib][0] = *(const bf16x8*)&q16[qb + quad * 8];
    qa[ib][1] = *(const bf16x8*)&q16[qb + 32 + quad * 8];
  }

  bf16x8 kpre[2], vpre[2];
  auto loadKV = [&](int jt) {
#pragma unroll
    for (int p = 0; p < 2; p++) {
      const int e = t + p * 512;
      kpre[p] = *(const bf16x8*)&k16[((size_t)bh * N_ + jt + (e >> 3)) * DH_ + (e & 7) * 8];
      vpre[p] = *(const bf16x8*)&vT16[((size_t)bh * DH_ + (e >> 4)) * N_ + jt + (e & 15) * 8];
    }
  };
  loadKV(0);

  f32x4 of[2][4];
#pragma unroll
  for (int ib = 0; ib < 2; ib++)
#pragma unroll
    for (int dt = 0; dt < 4; dt++) of[ib][dt] = (f32x4){0.f, 0.f, 0.f, 0.f};

  for (int jt = 0; jt < N_; jt += 128) {
    __syncthreads();
#pragma unroll
    for (int p = 0; p < 2; p++) {
      const int e = t + p * 512;
      { const int row = e >> 3, ch = e & 7;      // K: 128 rows x 8 chunks
        *(bf16x8*)&Ks[row * 64 + ((ch ^ ((row >> 2) & 7)) * 8)] = kpre[p]; }
      { const int d = e >> 4, ch = e & 15;       // V: 64 d-rows x 16 chunks
        *(bf16x8*)&Vs[d * 128 + ((ch ^ (d & 15)) * 8)] = vpre[p]; }
    }
    __syncthreads();
    if (jt + 128 < N_) loadKV(jt + 128);   // in flight during compute

    // Permuted K A-frags for window jw: m=c -> j-local jw*32 + 8*(c>>2)+s*4+(c&3)
    bf16x8 kf[2][2];
#pragma unroll
    for (int s = 0; s < 2; s++) {
      const int jr = jw * 32 + ((c >> 2) * 8) + s * 4 + (c & 3);
      const int swz = (jr >> 2) & 7;
      kf[s][0] = *(const bf16x8*)&Ks[jr * 64 + ((quad ^ swz) * 8)];
      kf[s][1] = *(const bf16x8*)&Ks[jr * 64 + (((4 + quad) ^ swz) * 8)];
    }
    // V B-frags: B[n=d][k=jj] = V~T[d][jw*32 + quad*8 + jj]
    bf16x8 vf[4];
#pragma unroll
    for (int dt = 0; dt < 4; dt++) {
      const int d = dt * 16 + c;
      vf[dt] = *(const bf16x8*)&Vs[d * 128 + (((jw * 4 + quad) ^ (d & 15)) * 8)];
    }

#pragma unroll
    for (int ib = 0; ib < 2; ib++) {
      // S^T halves: D[m][n=i=c]; set s covers j-local jw*32 + 8*quad + s*4 + r
      f32x4 s0 = {0.f, 0.f, 0.f, 0.f}, s1 = {0.f, 0.f, 0.f, 0.f};
      s0 = MFMA32(kf[0][0], qa[ib][0], s0);
      s0 = MFMA32(kf[0][1], qa[ib][1], s0);
      s1 = MFMA32(kf[1][0], qa[ib][0], s1);
      s1 = MFMA32(kf[1][1], qa[ib][1], s1);
      // P A-frag via v_exp + v_perm pair-pack: pf[jj] = P[i=c][jw*32+quad*8+jj]
      i32x4 pi;
      pi[0] = pack2bf(FAST_EXP2(s0[0]), FAST_EXP2(s0[1]));
      pi[1] = pack2bf(FAST_EXP2(s0[2]), FAST_EXP2(s0[3]));
      pi[2] = pack2bf(FAST_EXP2(s1[0]), FAST_EXP2(s1[1]));
      pi[3] = pack2bf(FAST_EXP2(s1[2]), FAST_EXP2(s1[3]));
      bf16x8 pf = *(bf16x8*)&pi;
#pragma unroll
      for (int dt = 0; dt < 4; dt++)
        of[ib][dt] = MFMA32(pf, vf[dt], of[ib][dt]);
    }
  }

  // Tree reduce over the 4 jw-waves per i-half (disjoint j). Ks/Vs dead.
  __syncthreads();
  if (jw >= 2) {
    float* dst = Rf + (iw * 2 + (jw - 2)) * 2048;
#pragma unroll
    for (int ib = 0; ib < 2; ib++)
#pragma unroll
      for (int dt = 0; dt < 4; dt++)
        *(f32x4*)&dst[lane * 32 + (((ib * 4 + dt) ^ (lane & 7)) * 4)] = of[ib][dt];
  }
  __syncthreads();
  if (jw < 2) {
    const float* src = Rf + (iw * 2 + jw) * 2048;
#pragma unroll
    for (int ib = 0; ib < 2; ib++)
#pragma unroll
      for (int dt = 0; dt < 4; dt++)
        of[ib][dt] += *(const f32x4*)&src[lane * 32 + (((ib * 4 + dt) ^ (lane & 7)) * 4)];
  }
  __syncthreads();
  if (jw == 1) {
    float* dst = Rf + iw * 2048;
#pragma unroll
    for (int ib = 0; ib < 2; ib++)
#pragma unroll
      for (int dt = 0; dt < 4; dt++)
        *(f32x4*)&dst[lane * 32 + (((ib * 4 + dt) ^ (lane & 7)) * 4)] = of[ib][dt];
  }
  __syncthreads();
  if (jw == 0) {
    const float* src = Rf + iw * 2048;
#pragma unroll
    for (int ib = 0; ib < 2; ib++)
#pragma unroll
      for (int dt = 0; dt < 4; dt++) {
        of[ib][dt] += *(const f32x4*)&src[lane * 32 + (((ib * 4 + dt) ^ (lane & 7)) * 4)];
#pragma unroll
        for (int r = 0; r < 4; r++)
          ob16[((size_t)bb * N_ + i0 + iw * 32 + ib * 16 + quad * 4 + r) * C_ +
               hh * DH_ + dt * 16 + c] = f2bf(of[ib][dt][r]);
      }
  }
}

// ---------------------------------------------------------------------------
// Kernel 6 (MFMA): out = o @ Wo + bo  (fp32 out).
// grid (256 rowtiles of 32, 2 col-halves of 128) = 512 blocks -> 2 blocks/CU.
// ---------------------------------------------------------------------------
__global__ __launch_bounds__(256) void outproj_kernel(
    const unsigned short* __restrict__ ob16, const unsigned short* __restrict__ WoT,
    const float* __restrict__ bo, float* __restrict__ out) {
  const int rt = blockIdx.x;
  const int ch2 = blockIdx.y;
  const int t = threadIdx.x;
  const int w = t >> 6, lane = t & 63, c = lane & 15, quad = lane >> 4;
  __shared__ unsigned short As[32 * 64];    // 4 KB
  __shared__ unsigned short Bs[128 * 64];   // 16 KB

  f32x4 acc[2][2];
#pragma unroll
  for (int mt = 0; mt < 2; mt++)
#pragma unroll
    for (int nt = 0; nt < 2; nt++) acc[mt][nt] = (f32x4){0.f, 0.f, 0.f, 0.f};

  for (int kt = 0; kt < C_; kt += 64) {
    __syncthreads();
    {
      const int row = t >> 3, ch = t & 7;
      *(bf16x8*)&As[row * 64 + ((ch ^ (row & 7)) * 8)] =
          *(const bf16x8*)&ob16[((size_t)rt * 32 + row) * C_ + kt + ch * 8];
    }
#pragma unroll
    for (int p = 0; p < 4; p++) {
      const int e = t + p * 256;
      const int row = e >> 3, ch = e & 7;
      *(bf16x8*)&Bs[row * 64 + ((ch ^ (row & 7)) * 8)] =
          *(const bf16x8*)&WoT[(size_t)(ch2 * 128 + row) * C_ + kt + ch * 8];
    }
    __syncthreads();
#pragma unroll
    for (int kh = 0; kh < 2; kh++) {
      bf16x8 a[2];
#pragma unroll
      for (int mt = 0; mt < 2; mt++) {
        const int i = mt * 16 + c;
        a[mt] = *(const bf16x8*)&As[i * 64 + (((kh * 4 + quad) ^ (i & 7)) * 8)];
      }
#pragma unroll
      for (int nt = 0; nt < 2; nt++) {
        const int n = w * 32 + nt * 16 + c;
        bf16x8 b = *(const bf16x8*)&Bs[n * 64 + (((kh * 4 + quad) ^ (n & 7)) * 8)];
        acc[0][nt] = MFMA32(a[0], b, acc[0][nt]);
        acc[1][nt] = MFMA32(a[1], b, acc[1][nt]);
      }
    }
  }
#pragma unroll
  for (int mt = 0; mt < 2; mt++)
#pragma unroll
    for (int nt = 0; nt < 2; nt++) {
      const int col = ch2 * 128 + w * 32 + nt * 16 + c;
      const float bias = bo[col];
#pragma unroll
      for (int r = 0; r < 4; r++)
        out[((size_t)rt * 32 + mt * 16 + quad * 4 + r) * C_ + col] = acc[mt][nt][r] + bias;
    }
}

// ---------------------------------------------------------------------------
extern "C" void kernel_launch(void* const* d_in, const int* in_sizes, int n_in,
                              void* d_out, int out_size, void* d_ws, size_t ws_size,
                              hipStream_t stream) {
  const float* x    = (const float*)d_in[0];
  const float* pos  = (const float*)d_in[1];
  const float* Wq   = (const float*)d_in[2];
  const float* bq   = (const float*)d_in[3];
  const float* Wk   = (const float*)d_in[4];
  const float* bk   = (const float*)d_in[5];
  const float* Wv   = (const float*)d_in[6];
  const float* bv   = (const float*)d_in[7];
  const float* Wo   = (const float*)d_in[8];
  const float* bo   = (const float*)d_in[9];
  const float* ln_g = (const float*)d_in[10];
  const float* ln_b = (const float*)d_in[11];
  float* out = (float*)d_out;

  // Workspace (u16): h16|q16|k16|vT16|ob16 (2M each) | W3T 196608 | WoT 65536
  const size_t SZ = (size_t)B_ * N_ * C_;   // 2097152
  unsigned short* h16  = (unsigned short*)d_ws;
  unsigned short* q16  = h16 + SZ;
  unsigned short* k16  = q16 + SZ;
  unsigned short* vT16 = k16 + SZ;
  unsigned short* ob16 = vT16 + SZ;
  unsigned short* W3T  = ob16 + SZ;
  unsigned short* WoT  = W3T + (size_t)H_ * 192 * 256;

  ln_kernel<<<B_ * N_ / 4, 256, 0, stream>>>(x, pos, ln_g, ln_b, h16);
  wconv_kernel<<<128, 256, 0, stream>>>(Wq, Wk, Wv, Wo, W3T, WoT);
  qkv_kernel<<<dim3(128, H_), 256, 0, stream>>>(h16, W3T, bq, bk, bv, q16, k16, vT16);
  colstats_kernel<<<1024, 256, 0, stream>>>(q16, k16, vT16);
  attnout_kernel<<<512, 512, 0, stream>>>(q16, k16, vT16, ob16);
  outproj_kernel<<<dim3(256, 2), 256, 0, stream>>>(ob16, WoT, bo, out);
}